// Round 19
// baseline (190.361 us; speedup 1.0000x reference)
//
#include <hip/hip_runtime.h>

typedef _Float16 f16;
typedef __attribute__((ext_vector_type(8))) _Float16 f16x8;
typedef __attribute__((ext_vector_type(16))) float f32x16;
typedef __attribute__((ext_vector_type(4))) unsigned u32x4;

#define MM 2048
#define DD 256
#define LOG2E 1.44269504088896340736f

__device__ __forceinline__ void gload_lds16(const void* g, void* l) {
    __builtin_amdgcn_global_load_lds(
        (const __attribute__((address_space(1))) unsigned int*)g,
        (__attribute__((address_space(3))) unsigned int*)l, 16, 0, 0);
}
__device__ __forceinline__ f32x16 mfma32(f16x8 a, f16x8 b, f32x16 c) {
    return __builtin_amdgcn_mfma_f32_32x32x16_f16(a, b, c, 0, 0, 0);
}
__device__ __forceinline__ void plswap(unsigned& a, unsigned& b) {
    asm volatile("v_permlane32_swap_b32 %0, %1" : "+v"(a), "+v"(b));
}
__device__ __forceinline__ unsigned pk2(float a, float b) {
    return __builtin_bit_cast(unsigned, __builtin_amdgcn_cvt_pkrtz(a, b));
}
__device__ __forceinline__ float max3(float a, float b, float c) {
    return fmaxf(fmaxf(a, b), c);  // clang fuses to v_max3_f32
}

// Prep (verified R2..R18): memory f32 [2048][256] -> two fp16 copies, 16B-unit layouts.
__global__ void prep_kernel(const float* __restrict__ mem,
                            f16* __restrict__ kprep, f16* __restrict__ vtprep) {
    int t = blockIdx.x * blockDim.x + threadIdx.x;
    if (t < 65536) {
        int b = t >> 10, r = t & 1023, u = r >> 5, kk = r & 31;
        const float* src = mem + (b * 32 + kk) * DD + u * 8;
        f16 o8[8];
#pragma unroll
        for (int e = 0; e < 8; ++e) o8[e] = (f16)src[e];
        *(f16x8*)(kprep + (size_t)t * 8) = *(f16x8*)o8;
    } else {
        int t2 = t - 65536;
        int b = t2 >> 10, r = t2 & 1023, u = r >> 8, d = r & 255;
        f16 o8[8];
#pragma unroll
        for (int e = 0; e < 8; ++e) o8[e] = (f16)mem[(b * 32 + u * 8 + e) * DD + d];
        *(f16x8*)(vtprep + (size_t)t2 * 8) = *(f16x8*)o8;
    }
}

// 256 blocks x 512 threads (8 waves x 32 q-rows), R16/R18 pair-unrolled
// structure (best: 150us). R19 bundle: (1) v_max3-fused max tree (depth 3),
// (2) in-place exp + add-tree row-sum, (3) pair-0 peeled -> branchless hot
// loop with wrapped stage indices (wrapped tiles land in unread ring slots;
// epilogue __syncthreads drains all in-flight LDS-DMA before endpgm).
__launch_bounds__(512, 2)
__global__ void attn_kernel(const float* __restrict__ q,
                            const f16* __restrict__ kprep,
                            const f16* __restrict__ vtprep,
                            float* __restrict__ out) {
    __shared__ __align__(16) f16 klds[4][8192];
    __shared__ __align__(16) f16 vtlds[4][8192];

    const int tid = threadIdx.x;
    const int w = __builtin_amdgcn_readfirstlane(tid >> 6);  // 0..7
    const int lane = tid & 63;
    const int h = lane >> 5;
    const int l31 = lane & 31;
    const int q0 = blockIdx.x * 256 + w * 32;

    // Q B-frags: qf[s] lane(h,l31) elem j = Q[q0+l31][16s+8h+j]  (col=q=l31)
    f16x8 qf[16];
#pragma unroll
    for (int s = 0; s < 16; ++s) {
        const float* src = q + (size_t)(q0 + l31) * DD + s * 16 + h * 8;
        float4 a = *(const float4*)src;
        float4 b2 = *(const float4*)(src + 4);
        f16 t8[8] = {(f16)a.x, (f16)a.y, (f16)a.z, (f16)a.w,
                     (f16)b2.x, (f16)b2.y, (f16)b2.z, (f16)b2.w};
        qf[s] = *(f16x8*)t8;
    }

    f32x16 o[8];
#pragma unroll
    for (int dt = 0; dt < 8; ++dt) o[dt] = (f32x16)(0.f);
    float lpart = 0.f, mrun = -1e30f;
    f16x8 pa0 = (f16x8)(f16)0.f, pa1 = (f16x8)(f16)0.f;  // P frags of prev tile

#define STAGE_K(t_)                                                       \
    do {                                                                  \
        const f16* s_ = kprep + (size_t)((t_)&63) * 8192;                 \
        _Pragma("unroll")                                                 \
        for (int i_ = 0; i_ < 2; ++i_)                                    \
            gload_lds16(s_ + i_ * 4096 + w * 512 + lane * 8,              \
                        &klds[(t_) & 3][i_ * 4096 + w * 512]);            \
    } while (0)
#define STAGE_VT(t_)                                                      \
    do {                                                                  \
        const f16* s_ = vtprep + (size_t)((t_)&63) * 8192;                \
        _Pragma("unroll")                                                 \
        for (int i_ = 0; i_ < 2; ++i_)                                    \
            gload_lds16(s_ + i_ * 4096 + w * 512 + lane * 8,              \
                        &vtlds[(t_) & 3][i_ * 4096 + w * 512]);           \
    } while (0)

// QK: s_ = K(t_) Q^T, 16 chained MFMAs (C: col=q=l31, row=k=(r&3)+8(r>>2)+4h)
#define QK(t_, s_)                                                            \
    do {                                                                      \
        const f16* kb_ = &klds[(t_) & 3][0];                                  \
        _Pragma("unroll")                                                     \
        for (int st_ = 0; st_ < 16; ++st_) {                                  \
            f16x8 ak_ = *(const f16x8*)(kb_ + ((2 * st_ + h) * 32 + l31) * 8);\
            s_ = mfma32(ak_, qf[st_], s_);                                    \
        }                                                                     \
    } while (0)

// PV: o += P(prev) V(t_), pa0/pa1 in regs, V from vtlds ring
#define PV(t_)                                                                 \
    do {                                                                       \
        const f16* vb_ = &vtlds[(t_) & 3][0];                                  \
        _Pragma("unroll")                                                      \
        for (int dt_ = 0; dt_ < 8; ++dt_) {                                    \
            f16x8 v0_ = *(const f16x8*)(vb_ + ((0 + h) * 256 + dt_ * 32 + l31) * 8); \
            f16x8 v1_ = *(const f16x8*)(vb_ + ((2 + h) * 256 + dt_ * 32 + l31) * 8); \
            o[dt_] = mfma32(pa0, v0_, o[dt_]);                                 \
            o[dt_] = mfma32(pa1, v1_, o[dt_]);                                 \
        }                                                                      \
    } while (0)

// softmax (base-2, defer-max): max3 tree, in-place exp, add-tree sum, P pack
#define SOFTMAX_PACK(s_)                                                       \
    do {                                                                       \
        float g0_ = max3(s_[0], s_[1], s_[2]);                                 \
        float g1_ = max3(s_[3], s_[4], s_[5]);                                 \
        float g2_ = max3(s_[6], s_[7], s_[8]);                                 \
        float g3_ = max3(s_[9], s_[10], s_[11]);                               \
        float g4_ = max3(s_[12], s_[13], s_[14]);                              \
        float sm_ = fmaxf(max3(g0_, g1_, g2_), max3(g3_, g4_, s_[15]));        \
        sm_ *= LOG2E;                                                          \
        if (__any(sm_ > mrun + 8.0f)) {                                        \
            sm_ = fmaxf(sm_, __shfl_xor(sm_, 32));                             \
            const float mn_ = fmaxf(mrun, sm_);                                \
            const float fct_ = __builtin_amdgcn_exp2f(mrun - mn_);             \
            mrun = mn_;                                                        \
            lpart *= fct_;                                                     \
            float fr_[16];                                                     \
            _Pragma("unroll") for (int r_ = 0; r_ < 16; ++r_)                  \
                fr_[r_] = __shfl(fct_, (r_ & 3) + 8 * (r_ >> 2) + 4 * h, 32);  \
            _Pragma("unroll") for (int dt_ = 0; dt_ < 8; ++dt_)                \
                _Pragma("unroll") for (int r_ = 0; r_ < 16; ++r_)              \
                    o[dt_][r_] *= fr_[r_];                                     \
        }                                                                      \
        _Pragma("unroll") for (int r_ = 0; r_ < 16; ++r_)                      \
            s_[r_] = __builtin_amdgcn_exp2f(                                   \
                __builtin_fmaf(s_[r_], LOG2E, -mrun));                         \
        float r0_ = (s_[0] + s_[1]) + (s_[2] + s_[3]);                         \
        float r1_ = (s_[4] + s_[5]) + (s_[6] + s_[7]);                         \
        float r2_ = (s_[8] + s_[9]) + (s_[10] + s_[11]);                       \
        float r3_ = (s_[12] + s_[13]) + (s_[14] + s_[15]);                     \
        lpart += (r0_ + r1_) + (r2_ + r3_);                                    \
        unsigned c0_ = pk2(s_[0], s_[1]), c1_ = pk2(s_[2], s_[3]);             \
        unsigned c2_ = pk2(s_[4], s_[5]), c3_ = pk2(s_[6], s_[7]);             \
        unsigned c4_ = pk2(s_[8], s_[9]), c5_ = pk2(s_[10], s_[11]);           \
        unsigned c6_ = pk2(s_[12], s_[13]), c7_ = pk2(s_[14], s_[15]);         \
        plswap(c0_, c2_); plswap(c1_, c3_);                                    \
        plswap(c4_, c6_); plswap(c5_, c7_);                                    \
        u32x4 k0_ = {c0_, c1_, c2_, c3_}, k1_ = {c4_, c5_, c6_, c7_};          \
        pa0 = __builtin_bit_cast(f16x8, k0_);                                  \
        pa1 = __builtin_bit_cast(f16x8, k1_);                                  \
    } while (0)

    // Prologue: K(0), K(1), VT(0) (drained by the pair-0 barrier).
    STAGE_K(0);
    STAGE_K(1);
    STAGE_VT(0);

    // ---- peeled pair 0: QK(0),SM,QK(1),PV(0),SM (no PV for tile 0)
    {
        __syncthreads();
        STAGE_K(2); STAGE_K(3);
        STAGE_VT(1); STAGE_VT(2);

        __builtin_amdgcn_s_setprio(1);
        f32x16 s0 = (f32x16)(0.f);
        QK(0, s0);
        __builtin_amdgcn_s_setprio(0);
        SOFTMAX_PACK(s0);

        __builtin_amdgcn_s_setprio(1);
        f32x16 s1 = (f32x16)(0.f);
        QK(1, s1);
        PV(0);
        __builtin_amdgcn_s_setprio(0);
        SOFTMAX_PACK(s1);
    }

    // ---- main loop p = 1..31: branchless; wrapped stage indices are benign
    for (int p = 1; p < 32; ++p) {
        const int t0 = 2 * p, t1 = 2 * p + 1;
        __syncthreads();
        if (w & 4) __builtin_amdgcn_s_sleep(8);  // SIMD-mate anti-phase skew
        STAGE_K(t0 + 2); STAGE_K(t1 + 2);   // pair 31 wraps to 0,1 (unread)
        STAGE_VT(t1); STAGE_VT(t1 + 1);     // pair 31: VT(64)->slot 0 (unread)

        __builtin_amdgcn_s_setprio(1);
        f32x16 s0 = (f32x16)(0.f);
        QK(t0, s0);
        PV(t0 - 1);
        __builtin_amdgcn_s_setprio(0);
        SOFTMAX_PACK(s0);

        __builtin_amdgcn_s_setprio(1);
        f32x16 s1 = (f32x16)(0.f);
        QK(t1, s1);
        PV(t0);
        __builtin_amdgcn_s_setprio(0);
        SOFTMAX_PACK(s1);
    }

    // Epilogue: PV(63) (VT(63) staged at pair 31; barrier drains everything,
    // including wrapped stages -- no in-flight DMA past endpgm).
    __syncthreads();
    __builtin_amdgcn_s_setprio(1);
    PV(63);
    __builtin_amdgcn_s_setprio(0);

    const float ltot = lpart + __shfl_xor(lpart, 32);
    const float inv = 1.0f / ltot;
    float invr[16];
#pragma unroll
    for (int r = 0; r < 16; ++r)
        invr[r] = __shfl(inv, (r & 3) + 8 * (r >> 2) + 4 * h, 32);
#pragma unroll
    for (int dt = 0; dt < 8; ++dt)
#pragma unroll
        for (int r = 0; r < 16; ++r) {
            const int qrow = (r & 3) + 8 * (r >> 2) + 4 * h;
            out[(size_t)(q0 + qrow) * DD + dt * 32 + l31] = o[dt][r] * invr[r];
        }
}

extern "C" void kernel_launch(void* const* d_in, const int* in_sizes, int n_in,
                              void* d_out, int out_size, void* d_ws, size_t ws_size,
                              hipStream_t stream) {
    const float* memory = (const float*)d_in[0];
    const float* query = (const float*)d_in[1];
    float* out = (float*)d_out;
    f16* kprep = (f16*)d_ws;                 // 1 MB
    f16* vtprep = kprep + (size_t)MM * DD;   // 1 MB
    prep_kernel<<<512, 256, 0, stream>>>(memory, kprep, vtprep);
    attn_kernel<<<256, 512, 0, stream>>>(query, kprep, vtprep, out);
}

// Round 20
// 150.672 us; speedup vs baseline: 1.2634x; 1.2634x over previous
//
#include <hip/hip_runtime.h>

typedef _Float16 f16;
typedef __attribute__((ext_vector_type(8))) _Float16 f16x8;
typedef __attribute__((ext_vector_type(16))) float f32x16;
typedef __attribute__((ext_vector_type(4))) unsigned u32x4;

#define MM 2048
#define DD 256
#define LOG2E 1.44269504088896340736f

__device__ __forceinline__ void gload_lds16(const void* g, void* l) {
    __builtin_amdgcn_global_load_lds(
        (const __attribute__((address_space(1))) unsigned int*)g,
        (__attribute__((address_space(3))) unsigned int*)l, 16, 0, 0);
}
__device__ __forceinline__ f32x16 mfma32(f16x8 a, f16x8 b, f32x16 c) {
    return __builtin_amdgcn_mfma_f32_32x32x16_f16(a, b, c, 0, 0, 0);
}
__device__ __forceinline__ void plswap(unsigned& a, unsigned& b) {
    asm volatile("v_permlane32_swap_b32 %0, %1" : "+v"(a), "+v"(b));
}
__device__ __forceinline__ unsigned pk2(float a, float b) {
    return __builtin_bit_cast(unsigned, __builtin_amdgcn_cvt_pkrtz(a, b));
}

// Prep (verified R2..R18): memory f32 [2048][256] -> two fp16 copies, 16B-unit layouts.
__global__ void prep_kernel(const float* __restrict__ mem,
                            f16* __restrict__ kprep, f16* __restrict__ vtprep) {
    int t = blockIdx.x * blockDim.x + threadIdx.x;
    if (t < 65536) {
        int b = t >> 10, r = t & 1023, u = r >> 5, kk = r & 31;
        const float* src = mem + (b * 32 + kk) * DD + u * 8;
        f16 o8[8];
#pragma unroll
        for (int e = 0; e < 8; ++e) o8[e] = (f16)src[e];
        *(f16x8*)(kprep + (size_t)t * 8) = *(f16x8*)o8;
    } else {
        int t2 = t - 65536;
        int b = t2 >> 10, r = t2 & 1023, u = r >> 8, d = r & 255;
        f16 o8[8];
#pragma unroll
        for (int e = 0; e < 8; ++e) o8[e] = (f16)mem[(b * 32 + u * 8 + e) * DD + d];
        *(f16x8*)(vtprep + (size_t)t2 * 8) = *(f16x8*)o8;
    }
}

// 256 blocks x 512 threads (8 waves x 32 q-rows), pair-unrolled R16 structure
// with SIMD-mate skew (R18, best: 150.4us). This is the verbatim R18 kernel --
// R19's softmax/peel bundle tipped the allocator into scratch spill (FETCH
// 41->88MB, WRITE 65->163MB) and was reverted.
__launch_bounds__(512, 2)
__global__ void attn_kernel(const float* __restrict__ q,
                            const f16* __restrict__ kprep,
                            const f16* __restrict__ vtprep,
                            float* __restrict__ out) {
    __shared__ __align__(16) f16 klds[4][8192];
    __shared__ __align__(16) f16 vtlds[4][8192];

    const int tid = threadIdx.x;
    const int w = __builtin_amdgcn_readfirstlane(tid >> 6);  // 0..7
    const int lane = tid & 63;
    const int h = lane >> 5;
    const int l31 = lane & 31;
    const int q0 = blockIdx.x * 256 + w * 32;

    // Q B-frags: qf[s] lane(h,l31) elem j = Q[q0+l31][16s+8h+j]  (col=q=l31)
    f16x8 qf[16];
#pragma unroll
    for (int s = 0; s < 16; ++s) {
        const float* src = q + (size_t)(q0 + l31) * DD + s * 16 + h * 8;
        float4 a = *(const float4*)src;
        float4 b2 = *(const float4*)(src + 4);
        f16 t8[8] = {(f16)a.x, (f16)a.y, (f16)a.z, (f16)a.w,
                     (f16)b2.x, (f16)b2.y, (f16)b2.z, (f16)b2.w};
        qf[s] = *(f16x8*)t8;
    }

    f32x16 o[8];
#pragma unroll
    for (int dt = 0; dt < 8; ++dt) o[dt] = (f32x16)(0.f);
    float lpart = 0.f, mrun = -1e30f;
    f16x8 pa0 = (f16x8)(f16)0.f, pa1 = (f16x8)(f16)0.f;  // P frags of prev tile

#define STAGE_K(t_)                                                       \
    do {                                                                  \
        const f16* s_ = kprep + (size_t)(t_)*8192;                        \
        _Pragma("unroll")                                                 \
        for (int i_ = 0; i_ < 2; ++i_)                                    \
            gload_lds16(s_ + i_ * 4096 + w * 512 + lane * 8,              \
                        &klds[(t_) & 3][i_ * 4096 + w * 512]);            \
    } while (0)
#define STAGE_VT(t_)                                                      \
    do {                                                                  \
        const f16* s_ = vtprep + (size_t)(t_)*8192;                       \
        _Pragma("unroll")                                                 \
        for (int i_ = 0; i_ < 2; ++i_)                                    \
            gload_lds16(s_ + i_ * 4096 + w * 512 + lane * 8,              \
                        &vtlds[(t_) & 3][i_ * 4096 + w * 512]);           \
    } while (0)

// QK: s_ = K(t_) Q^T, 16 chained MFMAs (C: col=q=l31, row=k=(r&3)+8(r>>2)+4h)
#define QK(t_, s_)                                                            \
    do {                                                                      \
        const f16* kb_ = &klds[(t_) & 3][0];                                  \
        _Pragma("unroll")                                                     \
        for (int st_ = 0; st_ < 16; ++st_) {                                  \
            f16x8 ak_ = *(const f16x8*)(kb_ + ((2 * st_ + h) * 32 + l31) * 8);\
            s_ = mfma32(ak_, qf[st_], s_);                                    \
        }                                                                     \
    } while (0)

// PV: o += P(prev) V(t_), pa0/pa1 in regs, V from vtlds ring
#define PV(t_)                                                                 \
    do {                                                                       \
        const f16* vb_ = &vtlds[(t_) & 3][0];                                  \
        _Pragma("unroll")                                                      \
        for (int dt_ = 0; dt_ < 8; ++dt_) {                                    \
            f16x8 v0_ = *(const f16x8*)(vb_ + ((0 + h) * 256 + dt_ * 32 + l31) * 8); \
            f16x8 v1_ = *(const f16x8*)(vb_ + ((2 + h) * 256 + dt_ * 32 + l31) * 8); \
            o[dt_] = mfma32(pa0, v0_, o[dt_]);                                 \
            o[dt_] = mfma32(pa1, v1_, o[dt_]);                                 \
        }                                                                      \
    } while (0)

// softmax (base-2, defer-max) + in-register P pack -> pa0/pa1
#define SOFTMAX_PACK(s_)                                                       \
    do {                                                                       \
        float sm_ = s_[0];                                                     \
        _Pragma("unroll") for (int r_ = 1; r_ < 16; ++r_)                      \
            sm_ = fmaxf(sm_, s_[r_]);                                          \
        sm_ *= LOG2E;                                                          \
        if (__any(sm_ > mrun + 8.0f)) {                                        \
            sm_ = fmaxf(sm_, __shfl_xor(sm_, 32));                             \
            const float mn_ = fmaxf(mrun, sm_);                                \
            const float fct_ = __builtin_amdgcn_exp2f(mrun - mn_);             \
            mrun = mn_;                                                        \
            lpart *= fct_;                                                     \
            float fr_[16];                                                     \
            _Pragma("unroll") for (int r_ = 0; r_ < 16; ++r_)                  \
                fr_[r_] = __shfl(fct_, (r_ & 3) + 8 * (r_ >> 2) + 4 * h, 32);  \
            _Pragma("unroll") for (int dt_ = 0; dt_ < 8; ++dt_)                \
                _Pragma("unroll") for (int r_ = 0; r_ < 16; ++r_)              \
                    o[dt_][r_] *= fr_[r_];                                     \
        }                                                                      \
        float p_[16], rs_ = 0.f;                                               \
        _Pragma("unroll") for (int r_ = 0; r_ < 16; ++r_) {                    \
            p_[r_] = __builtin_amdgcn_exp2f(                                   \
                __builtin_fmaf(s_[r_], LOG2E, -mrun));                         \
            rs_ += p_[r_];                                                     \
        }                                                                      \
        lpart += rs_;                                                          \
        unsigned c0_ = pk2(p_[0], p_[1]), c1_ = pk2(p_[2], p_[3]);             \
        unsigned c2_ = pk2(p_[4], p_[5]), c3_ = pk2(p_[6], p_[7]);             \
        unsigned c4_ = pk2(p_[8], p_[9]), c5_ = pk2(p_[10], p_[11]);           \
        unsigned c6_ = pk2(p_[12], p_[13]), c7_ = pk2(p_[14], p_[15]);         \
        plswap(c0_, c2_); plswap(c1_, c3_);                                    \
        plswap(c4_, c6_); plswap(c5_, c7_);                                    \
        u32x4 k0_ = {c0_, c1_, c2_, c3_}, k1_ = {c4_, c5_, c6_, c7_};          \
        pa0 = __builtin_bit_cast(f16x8, k0_);                                  \
        pa1 = __builtin_bit_cast(f16x8, k1_);                                  \
    } while (0)

    // Prologue: K(0), K(1), VT(0) (drained by the first in-loop barrier).
    STAGE_K(0);
    STAGE_K(1);
    STAGE_VT(0);

    // Main loop: 32 pairs; ONE barrier per pair; SIMD-mate skew after barrier.
    for (int p = 0; p < 32; ++p) {
        const int t0 = 2 * p, t1 = 2 * p + 1;
        __syncthreads();
        // Anti-phase the two waves sharing each SIMD (w and w+4): ~512 cyc,
        // about one ds_read burst, so their read/MFMA phases interleave.
        if (w & 4) __builtin_amdgcn_s_sleep(8);
        if (p < 31) { STAGE_K(t0 + 2); STAGE_K(t1 + 2); }
        STAGE_VT(t1);                 // first read: PV(t1) next pair
        if (p < 31) STAGE_VT(t1 + 1); // first read: PV(t1+1) next pair

        __builtin_amdgcn_s_setprio(1);
        f32x16 s0 = (f32x16)(0.f);
        QK(t0, s0);
        if (p) PV(t0 - 1);
        __builtin_amdgcn_s_setprio(0);
        SOFTMAX_PACK(s0);

        __builtin_amdgcn_s_setprio(1);
        f32x16 s1 = (f32x16)(0.f);
        QK(t1, s1);
        PV(t0);
        __builtin_amdgcn_s_setprio(0);
        SOFTMAX_PACK(s1);
    }

    // Epilogue: PV(63) (VT(63) staged at pair 31; barrier drains it).
    __syncthreads();
    __builtin_amdgcn_s_setprio(1);
    PV(63);
    __builtin_amdgcn_s_setprio(0);

    const float ltot = lpart + __shfl_xor(lpart, 32);
    const float inv = 1.0f / ltot;
    float invr[16];
#pragma unroll
    for (int r = 0; r < 16; ++r)
        invr[r] = __shfl(inv, (r & 3) + 8 * (r >> 2) + 4 * h, 32);
#pragma unroll
    for (int dt = 0; dt < 8; ++dt)
#pragma unroll
        for (int r = 0; r < 16; ++r) {
            const int qrow = (r & 3) + 8 * (r >> 2) + 4 * h;
            out[(size_t)(q0 + qrow) * DD + dt * 32 + l31] = o[dt][r] * invr[r];
        }
}

extern "C" void kernel_launch(void* const* d_in, const int* in_sizes, int n_in,
                              void* d_out, int out_size, void* d_ws, size_t ws_size,
                              hipStream_t stream) {
    const float* memory = (const float*)d_in[0];
    const float* query = (const float*)d_in[1];
    float* out = (float*)d_out;
    f16* kprep = (f16*)d_ws;                 // 1 MB
    f16* vtprep = kprep + (size_t)MM * DD;   // 1 MB
    prep_kernel<<<512, 256, 0, stream>>>(memory, kprep, vtprep);
    attn_kernel<<<256, 512, 0, stream>>>(query, kprep, vtprep, out);
}